// Round 1
// baseline (255.470 us; speedup 1.0000x reference)
//
#include <hip/hip_runtime.h>

typedef __bf16 bf16;
typedef __bf16 bf16x8 __attribute__((ext_vector_type(8)));
typedef __bf16 bf16x4 __attribute__((ext_vector_type(4)));
typedef float f32x4 __attribute__((ext_vector_type(4)));

// Problem constants
// x: [256][4096] f32, conv_w: [1536][256] f32, out: [512][4096] f32
// heads=8, per head channels [h*192, h*192+192): key [0:64), query [64:128), value [128:192)
// group g = channel/64  (24 groups == one group per section per head)

// ---------------- K0a: cast conv_w -> bf16 ----------------
__global__ void k_cast_w(const float* __restrict__ w, bf16* __restrict__ wb) {
    int idx = (blockIdx.x * 256 + threadIdx.x) * 4;
    float4 f = *(const float4*)(w + idx);
    bf16x4 o;
    o[0] = (bf16)f.x; o[1] = (bf16)f.y; o[2] = (bf16)f.z; o[3] = (bf16)f.w;
    *(bf16x4*)(wb + idx) = o;
}

// ---------------- K0b: transpose+cast x[c][p] -> xT[p][c] bf16 ----------------
__global__ void k_xpose(const float* __restrict__ x, bf16* __restrict__ xT) {
    int t = blockIdx.x * 256 + threadIdx.x;   // 131072 threads
    int p  = t & 4095;
    int c0 = (t >> 12) * 8;                   // 0..248
    bf16x8 o;
#pragma unroll
    for (int j = 0; j < 8; j++) o[j] = (bf16)x[(c0 + j) * 4096 + p];
    *(bf16x8*)(xT + p * 256 + c0) = o;
}

// ---------------- K1: conv GEMM attn[o][p] = sum_c W[o][c] x[c][p] ----------------
__global__ __launch_bounds__(256) void k_conv(const bf16* __restrict__ Wb,
                                              const bf16* __restrict__ xT,
                                              float* __restrict__ attn) {
    int wid = threadIdx.x >> 6, lane = threadIdx.x & 63;
    int quad = lane >> 4, l15 = lane & 15;
    int ob = (blockIdx.x % 24) * 64;
    int pb = (blockIdx.x / 24) * 64;
    int orow = ob + wid * 16 + l15;

    f32x4 acc[4];
#pragma unroll
    for (int c = 0; c < 4; c++) acc[c] = (f32x4){0.f, 0.f, 0.f, 0.f};

#pragma unroll
    for (int ks = 0; ks < 8; ks++) {
        bf16x8 a = *(const bf16x8*)(Wb + orow * 256 + ks * 32 + quad * 8);
#pragma unroll
        for (int c = 0; c < 4; c++) {
            bf16x8 b = *(const bf16x8*)(xT + (pb + c * 16 + l15) * 256 + ks * 32 + quad * 8);
            acc[c] = __builtin_amdgcn_mfma_f32_16x16x32_bf16(a, b, acc[c], 0, 0, 0);
        }
    }
    int orow2 = ob + wid * 16 + quad * 4;
#pragma unroll
    for (int c = 0; c < 4; c++)
#pragma unroll
        for (int r = 0; r < 4; r++)
            attn[(orow2 + r) * 4096 + pb + c * 16 + l15] = acc[c][r];
}

// ---------------- K2a: per-channel sum / sumsq ----------------
__global__ __launch_bounds__(256) void k_chanstats(const float* __restrict__ attn,
                                                   float2* __restrict__ cs) {
    int o = blockIdx.x;
    int t = threadIdx.x;
    const float4* row = (const float4*)(attn + o * 4096);
    float s = 0.f, ss = 0.f;
#pragma unroll
    for (int i = 0; i < 4; i++) {
        float4 v = row[i * 256 + t];
        s  += v.x + v.y + v.z + v.w;
        ss += v.x * v.x + v.y * v.y + v.z * v.z + v.w * v.w;
    }
#pragma unroll
    for (int m = 1; m < 64; m <<= 1) { s += __shfl_xor(s, m, 64); ss += __shfl_xor(ss, m, 64); }
    __shared__ float ls[4], lss[4];
    int wid = t >> 6;
    if ((t & 63) == 0) { ls[wid] = s; lss[wid] = ss; }
    __syncthreads();
    if (t == 0) cs[o] = make_float2(ls[0] + ls[1] + ls[2] + ls[3],
                                    lss[0] + lss[1] + lss[2] + lss[3]);
}

// ---------------- K2b: group mean / inv_std ----------------
__global__ void k_groupstats(const float2* __restrict__ cs, float2* __restrict__ gs) {
    int g = blockIdx.x, t = threadIdx.x;   // 64 threads
    float2 v = cs[g * 64 + t];
    float s = v.x, ss = v.y;
#pragma unroll
    for (int m = 1; m < 64; m <<= 1) { s += __shfl_xor(s, m, 64); ss += __shfl_xor(ss, m, 64); }
    if (t == 0) {
        const float N = 64.0f * 4096.0f;
        float mean = s / N;
        float var  = ss / N - mean * mean;
        gs[g] = make_float2(mean, rsqrtf(var + 1e-5f));
    }
}

// ---------------- K3: normalize + layout K^T / Q^T / V ----------------
// qkvT per head (262144 elems each): [QT [4096][64] | KT [4096][64] | V [64][4096]]
__global__ __launch_bounds__(256) void k_norm(const float* __restrict__ attn,
                                              const float2* __restrict__ gs,
                                              const float* __restrict__ gnw,
                                              const float* __restrict__ gnb,
                                              bf16* __restrict__ qkvT) {
    int bid = blockIdx.x;
    int pt  = bid & 63;
    int sec = (bid >> 6) % 3;      // 0=key 1=query 2=value
    int h   = bid / 192;
    int pb  = pt * 64;
    int ch0 = h * 192 + sec * 64;
    int g   = h * 3 + sec;
    float2 ms = gs[g];
    float mean = ms.x, inv = ms.y;
    int t = threadIdx.x;
    bf16* base = qkvT + h * 786432;

    if (sec == 2) {
        bf16* V = base + 524288;
#pragma unroll
        for (int i = 0; i < 16; i++) {
            int e = i * 256 + t; int kd = e >> 6; int p = e & 63;
            int o = ch0 + kd;
            float sc = inv * gnw[o];
            float sh = gnb[o] - mean * sc;
            float v = attn[o * 4096 + pb + p];
            V[kd * 4096 + pb + p] = (bf16)(v * sc + sh);
        }
    } else {
        __shared__ __attribute__((aligned(16))) bf16 tile[64 * 72];
#pragma unroll
        for (int i = 0; i < 16; i++) {
            int e = i * 256 + t; int kd = e >> 6; int p = e & 63;
            int o = ch0 + kd;
            float sc = inv * gnw[o];
            float sh = gnb[o] - mean * sc;
            float v = attn[o * 4096 + pb + p];
            tile[kd * 72 + p] = (bf16)(v * sc + sh);
        }
        __syncthreads();
        bf16* dst = base + (sec == 0 ? 262144 : 0);
#pragma unroll
        for (int c2 = 0; c2 < 2; c2++) {
            int ck = c2 * 256 + t;            // 0..511
            int p = ck >> 3; int ko = (ck & 7) * 8;
            bf16x8 o8;
#pragma unroll
            for (int j = 0; j < 8; j++) o8[j] = tile[(ko + j) * 72 + p];
            *(bf16x8*)(dst + (pb + p) * 64 + ko) = o8;
        }
    }
}

// ---------------- K4: flash attention ----------------
__global__ __launch_bounds__(256) void k_attn(const bf16* __restrict__ qkvT,
                                              float* __restrict__ out) {
    int h  = blockIdx.x >> 6;
    int qt = blockIdx.x & 63;
    int qbase = qt * 64;
    int wid = threadIdx.x >> 6, lane = threadIdx.x & 63;
    int quad = lane >> 4, l15 = lane & 15;
    const bf16* QT = qkvT + h * 786432;
    const bf16* KT = QT + 262144;
    const bf16* V  = QT + 524288;

    __shared__ __attribute__((aligned(16))) bf16 Ks[64 * 72];
    __shared__ __attribute__((aligned(16))) bf16 Vs[64 * 72];
    __shared__ __attribute__((aligned(16))) bf16 Ps[4][16 * 72];

    // Q A-fragments (loop-invariant): a[j] = Q^T[q][kd], contiguous in kd
    bf16x8 aq[2];
#pragma unroll
    for (int ks = 0; ks < 2; ks++)
        aq[ks] = *(const bf16x8*)(QT + (qbase + wid * 16 + l15) * 64 + ks * 32 + quad * 8);

    f32x4 o_acc[4];
#pragma unroll
    for (int c = 0; c < 4; c++) o_acc[c] = (f32x4){0.f, 0.f, 0.f, 0.f};
    float m[4]    = {-1e30f, -1e30f, -1e30f, -1e30f};
    float lsum[4] = {0.f, 0.f, 0.f, 0.f};

    const float SCALE = 0.125f * 1.44269504088896340736f;   // log2(e)/sqrt(64)

    for (int lt = 0; lt < 64; lt++) {
        int lbase = lt * 64;
        __syncthreads();
        // stage K^T tile [l][kd] and V tile [kd][l], stride 72 (pad)
#pragma unroll
        for (int rep = 0; rep < 2; rep++) {
            int ck = rep * 256 + threadIdx.x;      // 0..511
            int r = ck >> 3; int off = (ck & 7) * 8;
            *(bf16x8*)(Ks + r * 72 + off) = *(const bf16x8*)(KT + (lbase + r) * 64 + off);
            *(bf16x8*)(Vs + r * 72 + off) = *(const bf16x8*)(V + r * 4096 + lbase + off);
        }
        __syncthreads();

        // S = Q^T K  (64 q x 64 l per block; this wave: 16 q rows)
        f32x4 s[4];
#pragma unroll
        for (int lb = 0; lb < 4; lb++) s[lb] = (f32x4){0.f, 0.f, 0.f, 0.f};
#pragma unroll
        for (int ks = 0; ks < 2; ks++) {
#pragma unroll
            for (int lb = 0; lb < 4; lb++) {
                bf16x8 b = *(const bf16x8*)(Ks + (lb * 16 + l15) * 72 + ks * 32 + quad * 8);
                s[lb] = __builtin_amdgcn_mfma_f32_16x16x32_bf16(aq[ks], b, s[lb], 0, 0, 0);
            }
        }

        // online softmax, rows q = quad*4 + r
#pragma unroll
        for (int r = 0; r < 4; r++) {
            float t0 = fmaxf(fmaxf(s[0][r], s[1][r]), fmaxf(s[2][r], s[3][r])) * SCALE;
            t0 = fmaxf(t0, __shfl_xor(t0, 1));
            t0 = fmaxf(t0, __shfl_xor(t0, 2));
            t0 = fmaxf(t0, __shfl_xor(t0, 4));
            t0 = fmaxf(t0, __shfl_xor(t0, 8));
            float mnew = fmaxf(m[r], t0);
            float alpha = exp2f(m[r] - mnew);
            m[r] = mnew;
            float pv[4];
            float rs = 0.f;
#pragma unroll
            for (int lb = 0; lb < 4; lb++) {
                float p = exp2f(s[lb][r] * SCALE - mnew);
                pv[lb] = p; rs += p;
            }
            rs += __shfl_xor(rs, 1);
            rs += __shfl_xor(rs, 2);
            rs += __shfl_xor(rs, 4);
            rs += __shfl_xor(rs, 8);
            lsum[r] = lsum[r] * alpha + rs;
#pragma unroll
            for (int c = 0; c < 4; c++) o_acc[c][r] *= alpha;
#pragma unroll
            for (int lb = 0; lb < 4; lb++)
                Ps[wid][(quad * 4 + r) * 72 + lb * 16 + l15] = (bf16)pv[lb];
        }

        // O += P V^T   (A = P from LDS round-trip, B = V[kd][l])
#pragma unroll
        for (int ks = 0; ks < 2; ks++) {
            bf16x8 ap = *(const bf16x8*)(&Ps[wid][l15 * 72 + ks * 32 + quad * 8]);
#pragma unroll
            for (int c = 0; c < 4; c++) {
                bf16x8 b = *(const bf16x8*)(Vs + (c * 16 + l15) * 72 + ks * 32 + quad * 8);
                o_acc[c] = __builtin_amdgcn_mfma_f32_16x16x32_bf16(ap, b, o_acc[c], 0, 0, 0);
            }
        }
    }

    // epilogue: out[h*64 + kd][qbase + q], divide by softmax denom
#pragma unroll
    for (int c = 0; c < 4; c++) {
        f32x4 vout;
#pragma unroll
        for (int r = 0; r < 4; r++) vout[r] = o_acc[c][r] / lsum[r];
        *(f32x4*)(out + (h * 64 + c * 16 + l15) * 4096 + qbase + wid * 16 + quad * 4) = vout;
    }
}

extern "C" void kernel_launch(void* const* d_in, const int* in_sizes, int n_in,
                              void* d_out, int out_size, void* d_ws, size_t ws_size,
                              hipStream_t stream) {
    const float* x      = (const float*)d_in[0];
    const float* conv_w = (const float*)d_in[1];
    const float* gn_w   = (const float*)d_in[2];
    const float* gn_b   = (const float*)d_in[3];
    float* out = (float*)d_out;
    char* ws = (char*)d_ws;

    float*  attn = (float*)(ws);                    // 1536*4096 f32  = 24 MB
    bf16*   qkvT = (bf16*) (ws + 25165824);         // 6291456 bf16   = 12 MB
    bf16*   Wb   = (bf16*) (ws + 37748736);         // 1536*256 bf16  = 768 KB
    bf16*   xT   = (bf16*) (ws + 38535168);         // 4096*256 bf16  = 2 MB
    float2* cs   = (float2*)(ws + 40632320);        // 1536 float2
    float2* gs   = (float2*)(ws + 40644608);        // 24 float2

    hipLaunchKernelGGL(k_cast_w,     dim3(384),  dim3(256), 0, stream, conv_w, Wb);
    hipLaunchKernelGGL(k_xpose,      dim3(512),  dim3(256), 0, stream, x, xT);
    hipLaunchKernelGGL(k_conv,       dim3(1536), dim3(256), 0, stream, Wb, xT, attn);
    hipLaunchKernelGGL(k_chanstats,  dim3(1536), dim3(256), 0, stream, attn, cs);
    hipLaunchKernelGGL(k_groupstats, dim3(24),   dim3(64),  0, stream, cs, gs);
    hipLaunchKernelGGL(k_norm,       dim3(1536), dim3(256), 0, stream, attn, gs, gn_w, gn_b, qkvT);
    hipLaunchKernelGGL(k_attn,       dim3(512),  dim3(256), 0, stream, qkvT, out);
}

// Round 2
// 187.228 us; speedup vs baseline: 1.3645x; 1.3645x over previous
//
#include <hip/hip_runtime.h>

typedef __bf16 bf16;
typedef __bf16 bf16x8 __attribute__((ext_vector_type(8)));
typedef __bf16 bf16x4 __attribute__((ext_vector_type(4)));
typedef float f32x4 __attribute__((ext_vector_type(4)));

// x: [256][4096] f32, conv_w: [1536][256] f32, out: [512][4096] f32
// heads=8; per head channels: key [0:64), query [64:128), value [128:192)
// softmax scale log2(e)/sqrt(64) is pre-folded into Q in k_norm.

// ---------------- K0a: cast conv_w -> bf16 ----------------
__global__ void k_cast_w(const float* __restrict__ w, bf16* __restrict__ wb) {
    int idx = (blockIdx.x * 256 + threadIdx.x) * 4;
    float4 f = *(const float4*)(w + idx);
    bf16x4 o;
    o[0] = (bf16)f.x; o[1] = (bf16)f.y; o[2] = (bf16)f.z; o[3] = (bf16)f.w;
    *(bf16x4*)(wb + idx) = o;
}

// ---------------- K0b: transpose+cast x[c][p] -> xT[p][c] bf16 ----------------
__global__ void k_xpose(const float* __restrict__ x, bf16* __restrict__ xT) {
    int t = blockIdx.x * 256 + threadIdx.x;
    int p  = t & 4095;
    int c0 = (t >> 12) * 8;
    bf16x8 o;
#pragma unroll
    for (int j = 0; j < 8; j++) o[j] = (bf16)x[(c0 + j) * 4096 + p];
    *(bf16x8*)(xT + p * 256 + c0) = o;
}

// ---------------- K0c: zero channel-stats accumulator ----------------
__global__ void k_zero(float* __restrict__ cs) {
#pragma unroll
    for (int i = 0; i < 12; i++) cs[i * 256 + threadIdx.x] = 0.f;
}

// ---------------- K1: conv GEMM + fused per-channel partial stats ----------------
__global__ __launch_bounds__(256) void k_conv(const bf16* __restrict__ Wb,
                                              const bf16* __restrict__ xT,
                                              float* __restrict__ attn,
                                              float* __restrict__ cs) {
    int wid = threadIdx.x >> 6, lane = threadIdx.x & 63;
    int quad = lane >> 4, l15 = lane & 15;
    int ob = (blockIdx.x % 24) * 64;
    int pb = (blockIdx.x / 24) * 64;
    int orow = ob + wid * 16 + l15;

    f32x4 acc[4];
#pragma unroll
    for (int c = 0; c < 4; c++) acc[c] = (f32x4){0.f, 0.f, 0.f, 0.f};

#pragma unroll
    for (int ks = 0; ks < 8; ks++) {
        bf16x8 a = *(const bf16x8*)(Wb + orow * 256 + ks * 32 + quad * 8);
#pragma unroll
        for (int c = 0; c < 4; c++) {
            bf16x8 b = *(const bf16x8*)(xT + (pb + c * 16 + l15) * 256 + ks * 32 + quad * 8);
            acc[c] = __builtin_amdgcn_mfma_f32_16x16x32_bf16(a, b, acc[c], 0, 0, 0);
        }
    }
    int orow2 = ob + wid * 16 + quad * 4;
#pragma unroll
    for (int c = 0; c < 4; c++)
#pragma unroll
        for (int r = 0; r < 4; r++)
            attn[(orow2 + r) * 4096 + pb + c * 16 + l15] = acc[c][r];

    // per-channel partial sums over this block's 64 pixels -> atomics
#pragma unroll
    for (int r = 0; r < 4; r++) {
        float sp  = acc[0][r] + acc[1][r] + acc[2][r] + acc[3][r];
        float ssp = acc[0][r] * acc[0][r] + acc[1][r] * acc[1][r]
                  + acc[2][r] * acc[2][r] + acc[3][r] * acc[3][r];
#pragma unroll
        for (int m = 1; m < 16; m <<= 1) {
            sp  += __shfl_xor(sp,  m, 64);
            ssp += __shfl_xor(ssp, m, 64);
        }
        if (l15 == 0) {
            atomicAdd(cs + (orow2 + r) * 2,     sp);
            atomicAdd(cs + (orow2 + r) * 2 + 1, ssp);
        }
    }
}

// ---------------- K2: group mean / inv_std ----------------
__global__ void k_groupstats(const float2* __restrict__ cs, float2* __restrict__ gs) {
    int g = blockIdx.x, t = threadIdx.x;   // 64 threads
    float2 v = cs[g * 64 + t];
    float s = v.x, ss = v.y;
#pragma unroll
    for (int m = 1; m < 64; m <<= 1) { s += __shfl_xor(s, m, 64); ss += __shfl_xor(ss, m, 64); }
    if (t == 0) {
        const float N = 64.0f * 4096.0f;
        float mean = s / N;
        float var  = ss / N - mean * mean;
        gs[g] = make_float2(mean, rsqrtf(var + 1e-5f));
    }
}

// ---------------- K3: normalize + layout Q^T / K^T / V (Q pre-scaled) ----------------
// qkvT per head: [QT [4096][64] | KT [4096][64] | V [64][4096]]
__global__ __launch_bounds__(256) void k_norm(const float* __restrict__ attn,
                                              const float2* __restrict__ gs,
                                              const float* __restrict__ gnw,
                                              const float* __restrict__ gnb,
                                              bf16* __restrict__ qkvT) {
    int bid = blockIdx.x;
    int pt  = bid & 63;
    int sec = (bid >> 6) % 3;      // 0=key 1=query 2=value
    int h   = bid / 192;
    int pb  = pt * 64;
    int ch0 = h * 192 + sec * 64;
    int g   = h * 3 + sec;
    float2 ms = gs[g];
    float mean = ms.x, inv = ms.y;
    float f = (sec == 1) ? 0.125f * 1.44269504088896340736f : 1.0f;
    int t = threadIdx.x;
    bf16* base = qkvT + h * 786432;

    if (sec == 2) {
        bf16* V = base + 524288;
#pragma unroll
        for (int i = 0; i < 16; i++) {
            int e = i * 256 + t; int kd = e >> 6; int p = e & 63;
            int o = ch0 + kd;
            float sc = inv * gnw[o];
            float sh = gnb[o] - mean * sc;
            float v = attn[o * 4096 + pb + p];
            V[kd * 4096 + pb + p] = (bf16)(v * sc + sh);
        }
    } else {
        __shared__ __attribute__((aligned(16))) bf16 tile[64 * 72];
#pragma unroll
        for (int i = 0; i < 16; i++) {
            int e = i * 256 + t; int kd = e >> 6; int p = e & 63;
            int o = ch0 + kd;
            float sc = inv * gnw[o] * f;
            float sh = gnb[o] * f - mean * sc;
            float v = attn[o * 4096 + pb + p];
            tile[kd * 72 + p] = (bf16)(v * sc + sh);
        }
        __syncthreads();
        bf16* dst = base + (sec == 0 ? 262144 : 0);
#pragma unroll
        for (int c2 = 0; c2 < 2; c2++) {
            int ck = c2 * 256 + t;
            int p = ck >> 3; int ko = (ck & 7) * 8;
            bf16x8 o8;
#pragma unroll
            for (int j = 0; j < 8; j++) o8[j] = tile[(ko + j) * 72 + p];
            *(bf16x8*)(dst + (pb + p) * 64 + ko) = o8;
        }
    }
}

// ---------------- K4: flash attention (S^T form, no-max softmax, 2-way L split) ----------------
__global__ __launch_bounds__(256, 4) void k_attn(const bf16* __restrict__ qkvT,
                                                 float* __restrict__ Opart,
                                                 float* __restrict__ Lsum) {
    int bid   = blockIdx.x;
    int split = bid & 1;
    int qt    = (bid >> 1) & 63;
    int h     = bid >> 7;
    int qbase = qt * 64;
    int wid = threadIdx.x >> 6, lane = threadIdx.x & 63;
    int quad = lane >> 4, l15 = lane & 15;
    const bf16* QT = qkvT + h * 786432;
    const bf16* KT = QT + 262144;
    const bf16* V  = QT + 524288;

    __shared__ __attribute__((aligned(16))) bf16 Ks[64 * 72];
    __shared__ __attribute__((aligned(16))) bf16 Vs[64 * 72];
    __shared__ __attribute__((aligned(16))) bf16 Ps[4][16 * 72];

    // Q B-fragment (loop-invariant): B[n=q][k=kd]
    bf16x8 bq[2];
#pragma unroll
    for (int ks = 0; ks < 2; ks++)
        bq[ks] = *(const bf16x8*)(QT + (qbase + wid * 16 + l15) * 64 + ks * 32 + quad * 8);

    f32x4 o_acc[4];
#pragma unroll
    for (int c = 0; c < 4; c++) o_acc[c] = (f32x4){0.f, 0.f, 0.f, 0.f};
    float ls = 0.f;

    for (int lt = 0; lt < 32; lt++) {
        int lbase = split * 2048 + lt * 64;
        __syncthreads();
#pragma unroll
        for (int rep = 0; rep < 2; rep++) {
            int ck = rep * 256 + threadIdx.x;
            int r = ck >> 3; int off = (ck & 7) * 8;
            *(bf16x8*)(Ks + r * 72 + off) = *(const bf16x8*)(KT + (lbase + r) * 64 + off);
            *(bf16x8*)(Vs + r * 72 + off) = *(const bf16x8*)(V + r * 4096 + lbase + off);
        }
        __syncthreads();

        // S^T = K Q : C row = l (quad*4+r within lb-block), col = q (l15)
        f32x4 s[4];
#pragma unroll
        for (int lb = 0; lb < 4; lb++) s[lb] = (f32x4){0.f, 0.f, 0.f, 0.f};
#pragma unroll
        for (int ks = 0; ks < 2; ks++) {
#pragma unroll
            for (int lb = 0; lb < 4; lb++) {
                bf16x8 ak = *(const bf16x8*)(Ks + (lb * 16 + l15) * 72 + ks * 32 + quad * 8);
                s[lb] = __builtin_amdgcn_mfma_f32_16x16x32_bf16(ak, bq[ks], s[lb], 0, 0, 0);
            }
        }

        // P = exp2(S^T): pure in-lane, pack bf16x4, write Ps[q][l]
#pragma unroll
        for (int lb = 0; lb < 4; lb++) {
            float p0 = exp2f(s[lb][0]);
            float p1 = exp2f(s[lb][1]);
            float p2 = exp2f(s[lb][2]);
            float p3 = exp2f(s[lb][3]);
            ls += (p0 + p1) + (p2 + p3);
            bf16x4 pk;
            pk[0] = (bf16)p0; pk[1] = (bf16)p1; pk[2] = (bf16)p2; pk[3] = (bf16)p3;
            *(bf16x4*)(&Ps[wid][l15 * 72 + lb * 16 + quad * 4]) = pk;
        }

        // O += P V^T : A[m=q][k=l] from Ps[q][l], B[n=kd][k=l] from Vs[kd][l]
#pragma unroll
        for (int ks = 0; ks < 2; ks++) {
            bf16x8 ap = *(const bf16x8*)(&Ps[wid][l15 * 72 + ks * 32 + quad * 8]);
#pragma unroll
            for (int c = 0; c < 4; c++) {
                bf16x8 bv = *(const bf16x8*)(Vs + (c * 16 + l15) * 72 + ks * 32 + quad * 8);
                o_acc[c] = __builtin_amdgcn_mfma_f32_16x16x32_bf16(ap, bv, o_acc[c], 0, 0, 0);
            }
        }
    }

    // row-sum reduction across the 4 quads (lanes sharing l15)
    ls += __shfl_xor(ls, 16, 64);
    ls += __shfl_xor(ls, 32, 64);
    if (lane < 16)
        Lsum[split * 32768 + h * 4096 + qbase + wid * 16 + lane] = ls;

    // partial O (unnormalized): row = h*64+kd, col = q
    float* Ob = Opart + split * 2097152;
#pragma unroll
    for (int c = 0; c < 4; c++)
        *(f32x4*)(Ob + (h * 64 + c * 16 + l15) * 4096 + qbase + wid * 16 + quad * 4) = o_acc[c];
}

// ---------------- K5: combine splits + normalize ----------------
__global__ void k_final(const float* __restrict__ Opart, const float* __restrict__ Lsum,
                        float* __restrict__ out) {
    int gid = blockIdx.x * 256 + threadIdx.x;     // 524288
    int row = gid >> 10;
    int c4  = (gid & 1023) << 2;
    int h   = row >> 6;
    float4 o0 = *(const float4*)(Opart + row * 4096 + c4);
    float4 o1 = *(const float4*)(Opart + 2097152 + row * 4096 + c4);
    float4 l0 = *(const float4*)(Lsum + h * 4096 + c4);
    float4 l1 = *(const float4*)(Lsum + 32768 + h * 4096 + c4);
    float4 r;
    r.x = (o0.x + o1.x) / (l0.x + l1.x);
    r.y = (o0.y + o1.y) / (l0.y + l1.y);
    r.z = (o0.z + o1.z) / (l0.z + l1.z);
    r.w = (o0.w + o1.w) / (l0.w + l1.w);
    *(float4*)(out + row * 4096 + c4) = r;
}

extern "C" void kernel_launch(void* const* d_in, const int* in_sizes, int n_in,
                              void* d_out, int out_size, void* d_ws, size_t ws_size,
                              hipStream_t stream) {
    const float* x      = (const float*)d_in[0];
    const float* conv_w = (const float*)d_in[1];
    const float* gn_w   = (const float*)d_in[2];
    const float* gn_b   = (const float*)d_in[3];
    float* out = (float*)d_out;
    char* ws = (char*)d_ws;

    float*  attn = (float*)(ws);                    // 1536*4096 f32 = 24 MB
    float*  Opart = (float*)(ws);                   // aliases attn (dead by k_attn): 2x8 MB
    bf16*   qkvT = (bf16*) (ws + 25165824);         // 12 MB
    bf16*   Wb   = (bf16*) (ws + 37748736);         // 768 KB
    bf16*   xT   = (bf16*) (ws + 38535168);         // 2 MB
    float*  cs   = (float*)(ws + 40632320);         // 1536 float2 = 12 KB
    float2* gs   = (float2*)(ws + 40644608);        // 24 float2
    float*  Lsum = (float*)(ws + 40645120);         // 2*32768 f32 = 256 KB

    hipLaunchKernelGGL(k_cast_w,     dim3(384),  dim3(256), 0, stream, conv_w, Wb);
    hipLaunchKernelGGL(k_xpose,      dim3(512),  dim3(256), 0, stream, x, xT);
    hipLaunchKernelGGL(k_zero,       dim3(1),    dim3(256), 0, stream, cs);
    hipLaunchKernelGGL(k_conv,       dim3(1536), dim3(256), 0, stream, Wb, xT, attn, cs);
    hipLaunchKernelGGL(k_groupstats, dim3(24),   dim3(64),  0, stream, (const float2*)cs, gs);
    hipLaunchKernelGGL(k_norm,       dim3(1536), dim3(256), 0, stream, attn, gs, gn_w, gn_b, qkvT);
    hipLaunchKernelGGL(k_attn,       dim3(1024), dim3(256), 0, stream, qkvT, Opart, Lsum);
    hipLaunchKernelGGL(k_final,      dim3(2048), dim3(256), 0, stream, Opart, Lsum, out);
}

// Round 3
// 178.491 us; speedup vs baseline: 1.4313x; 1.0489x over previous
//
#include <hip/hip_runtime.h>

typedef __bf16 bf16;
typedef __bf16 bf16x8 __attribute__((ext_vector_type(8)));
typedef __bf16 bf16x4 __attribute__((ext_vector_type(4)));
typedef float f32x4 __attribute__((ext_vector_type(4)));

// x: [256][4096] f32, conv_w: [1536][256] f32, out: [512][4096] f32
// heads=8; channels per head: key [0:64), query [64:128), value [128:192)
// qkvT per head (786432 elems): [QT(query) [4096][64] | KT(key) [4096][64] | V [64][4096]]
// Stored PRE-normalization by k_conv; k_norm applies per-channel affine in place.
// Softmax scale log2(e)/8 folded into query's affine coefficients.

// ---------------- K_misc: xpose + cast_w + zero(cs), fused ----------------
__global__ void k_misc(const float* __restrict__ x, const float* __restrict__ w,
                       bf16* __restrict__ xT, bf16* __restrict__ wb, float* __restrict__ cs) {
    int b = blockIdx.x;
    if (b < 512) {                       // transpose+cast x[c][p] -> xT[p][c]
        int t = b * 256 + threadIdx.x;
        int p  = t & 4095;
        int c0 = (t >> 12) * 8;
        bf16x8 o;
#pragma unroll
        for (int j = 0; j < 8; j++) o[j] = (bf16)x[(c0 + j) * 4096 + p];
        *(bf16x8*)(xT + p * 256 + c0) = o;
    } else if (b < 896) {                // cast conv_w -> bf16
        int idx = ((b - 512) * 256 + threadIdx.x) * 4;
        float4 f = *(const float4*)(w + idx);
        bf16x4 o;
        o[0] = (bf16)f.x; o[1] = (bf16)f.y; o[2] = (bf16)f.z; o[3] = (bf16)f.w;
        *(bf16x4*)(wb + idx) = o;
    } else {                             // zero channel stats
#pragma unroll
        for (int i = 0; i < 12; i++) cs[i * 256 + threadIdx.x] = 0.f;
    }
}

// ---------------- K1: conv GEMM -> direct QKV layouts + channel stats ----------------
__global__ __launch_bounds__(256) void k_conv(const bf16* __restrict__ Wb,
                                              const bf16* __restrict__ xT,
                                              bf16* __restrict__ qkvT,
                                              float* __restrict__ cs) {
    int wid = threadIdx.x >> 6, lane = threadIdx.x & 63;
    int quad = lane >> 4, l15 = lane & 15;
    int g  = blockIdx.x % 24;            // group == 64-channel block
    int pb = (blockIdx.x / 24) * 64;
    int h = g / 3, sec = g % 3;          // 0=key 1=query 2=value
    int ob = g * 64;
    int orow = ob + wid * 16 + l15;

    f32x4 acc[4];
#pragma unroll
    for (int c = 0; c < 4; c++) acc[c] = (f32x4){0.f, 0.f, 0.f, 0.f};

#pragma unroll
    for (int ks = 0; ks < 8; ks++) {
        bf16x8 a = *(const bf16x8*)(Wb + orow * 256 + ks * 32 + quad * 8);
#pragma unroll
        for (int c = 0; c < 4; c++) {
            bf16x8 b = *(const bf16x8*)(xT + (pb + c * 16 + l15) * 256 + ks * 32 + quad * 8);
            acc[c] = __builtin_amdgcn_mfma_f32_16x16x32_bf16(a, b, acc[c], 0, 0, 0);
        }
    }

    // stats from f32 accumulators (per global channel), atomics
    int orow2 = ob + wid * 16 + quad * 4;
#pragma unroll
    for (int r = 0; r < 4; r++) {
        float sp  = acc[0][r] + acc[1][r] + acc[2][r] + acc[3][r];
        float ssp = acc[0][r] * acc[0][r] + acc[1][r] * acc[1][r]
                  + acc[2][r] * acc[2][r] + acc[3][r] * acc[3][r];
#pragma unroll
        for (int m = 1; m < 16; m <<= 1) {
            sp  += __shfl_xor(sp,  m, 64);
            ssp += __shfl_xor(ssp, m, 64);
        }
        if (l15 == 0) {
            atomicAdd(cs + (orow2 + r) * 2,     sp);
            atomicAdd(cs + (orow2 + r) * 2 + 1, ssp);
        }
    }

    // store pre-norm bf16 directly into attention layouts
    bf16* base = qkvT + h * 786432;
    int kd0 = wid * 16 + quad * 4;       // lane's 4 kd rows
    if (sec == 2) {
        bf16* V = base + 524288;
#pragma unroll
        for (int c = 0; c < 4; c++)
#pragma unroll
            for (int r = 0; r < 4; r++)
                V[(kd0 + r) * 4096 + pb + c * 16 + l15] = (bf16)acc[c][r];
    } else {
        bf16* dst = base + (sec == 0 ? 262144 : 0);
#pragma unroll
        for (int c = 0; c < 4; c++) {
            bf16x4 o;
#pragma unroll
            for (int r = 0; r < 4; r++) o[r] = (bf16)acc[c][r];
            *(bf16x4*)(dst + (pb + c * 16 + l15) * 64 + kd0) = o;
        }
    }
}

// ---------------- K2: group stats -> per-channel affine (a,b) table ----------------
__global__ void k_stats(const float2* __restrict__ cs, const float* __restrict__ gnw,
                        const float* __restrict__ gnb, float2* __restrict__ ab) {
    int g = blockIdx.x, t = threadIdx.x;   // 24 x 64
    float2 v = cs[g * 64 + t];
    float s = v.x, ss = v.y;
#pragma unroll
    for (int m = 1; m < 64; m <<= 1) { s += __shfl_xor(s, m, 64); ss += __shfl_xor(ss, m, 64); }
    const float N = 64.0f * 4096.0f;
    float mean = s / N;
    float inv  = rsqrtf(ss / N - mean * mean + 1e-5f);
    float f = (g % 3 == 1) ? 0.18033688011112042f : 1.0f;   // log2(e)/8 folded into query
    int ch = g * 64 + t;
    float a = inv * gnw[ch] * f;
    float b = (gnb[ch] - mean * inv * gnw[ch]) * f;
    ab[ch] = make_float2(a, b);
}

// ---------------- K3: in-place elementwise normalization of qkvT ----------------
__global__ __launch_bounds__(256) void k_norm(bf16* __restrict__ qkv,
                                              const float2* __restrict__ ab) {
    int h = blockIdx.x / 384;
    int e = ((blockIdx.x % 384) * 256 + threadIdx.x) * 8;
    bf16* p = qkv + h * 786432 + e;
    bf16x8 v = *(bf16x8*)p;
    bf16x8 o;
    if (e >= 524288) {                    // value: one channel per 8
        float2 sv = ab[h * 192 + 128 + ((e - 524288) >> 12)];
#pragma unroll
        for (int j = 0; j < 8; j++) o[j] = (bf16)(sv.x * (float)v[j] + sv.y);
    } else {                              // query/key: 8 consecutive kd channels
        int cb = h * 192 + ((e < 262144) ? 64 : 0) + (e & 63);
#pragma unroll
        for (int j = 0; j < 8; j++) {
            float2 sv = ab[cb + j];
            o[j] = (bf16)(sv.x * (float)v[j] + sv.y);
        }
    }
    *(bf16x8*)p = o;
}

// ---------------- K4: flash attention, 256-q WG, 4-way L split ----------------
__global__ __launch_bounds__(256, 2) void k_attn(const bf16* __restrict__ qkvT,
                                                 bf16* __restrict__ Opart,
                                                 float* __restrict__ Lsum) {
    int bid   = blockIdx.x;
    int h     = bid & 7;                  // head on low bits: XCD L2 affinity
    int qb    = (bid >> 3) & 15;
    int split = bid >> 7;                 // 0..3
    int wid = threadIdx.x >> 6, lane = threadIdx.x & 63;
    int quad = lane >> 4, l15 = lane & 15;
    const bf16* QT = qkvT + h * 786432;
    const bf16* KT = QT + 262144;
    const bf16* V  = QT + 524288;
    int qw = qb * 256 + wid * 64;         // wave's q base (64 q per wave)

    __shared__ __attribute__((aligned(16))) bf16 Ks[64 * 72];
    __shared__ __attribute__((aligned(16))) bf16 Vs[64 * 72];
    __shared__ __attribute__((aligned(16))) bf16 Ps[4][64 * 72];

    // Q B-fragments, loop-invariant: 4 q-subtiles x 2 k-steps
    bf16x8 bq[4][2];
#pragma unroll
    for (int qs = 0; qs < 4; qs++)
#pragma unroll
        for (int ks = 0; ks < 2; ks++)
            bq[qs][ks] = *(const bf16x8*)(QT + (qw + qs * 16 + l15) * 64 + ks * 32 + quad * 8);

    f32x4 oacc[4][4];                     // [c=kd-block][qs]
#pragma unroll
    for (int c = 0; c < 4; c++)
#pragma unroll
        for (int qs = 0; qs < 4; qs++) oacc[c][qs] = (f32x4){0.f, 0.f, 0.f, 0.f};
    float ls[4] = {0.f, 0.f, 0.f, 0.f};

    for (int lt = 0; lt < 16; lt++) {
        int lbase = split * 1024 + lt * 64;
        __syncthreads();
#pragma unroll
        for (int rep = 0; rep < 2; rep++) {
            int ck = rep * 256 + threadIdx.x;
            int r = ck >> 3; int off = (ck & 7) * 8;
            *(bf16x8*)(Ks + r * 72 + off) = *(const bf16x8*)(KT + (lbase + r) * 64 + off);
            *(bf16x8*)(Vs + r * 72 + off) = *(const bf16x8*)(V + r * 4096 + lbase + off);
        }
        __syncthreads();

        // K A-fragments: read once, reused across 4 q-subtiles
        bf16x8 ak[2][4];
#pragma unroll
        for (int ks = 0; ks < 2; ks++)
#pragma unroll
            for (int lb = 0; lb < 4; lb++)
                ak[ks][lb] = *(const bf16x8*)(Ks + (lb * 16 + l15) * 72 + ks * 32 + quad * 8);

        // S^T = K·Q  -> P = exp2(S^T) -> Ps[q][l] (per-wave private, no barrier)
#pragma unroll
        for (int qs = 0; qs < 4; qs++) {
            f32x4 s[4];
#pragma unroll
            for (int lb = 0; lb < 4; lb++) s[lb] = (f32x4){0.f, 0.f, 0.f, 0.f};
#pragma unroll
            for (int ks = 0; ks < 2; ks++)
#pragma unroll
                for (int lb = 0; lb < 4; lb++)
                    s[lb] = __builtin_amdgcn_mfma_f32_16x16x32_bf16(ak[ks][lb], bq[qs][ks], s[lb], 0, 0, 0);
#pragma unroll
            for (int lb = 0; lb < 4; lb++) {
                float p0 = exp2f(s[lb][0]);
                float p1 = exp2f(s[lb][1]);
                float p2 = exp2f(s[lb][2]);
                float p3 = exp2f(s[lb][3]);
                ls[qs] += (p0 + p1) + (p2 + p3);
                bf16x4 pk;
                pk[0] = (bf16)p0; pk[1] = (bf16)p1; pk[2] = (bf16)p2; pk[3] = (bf16)p3;
                *(bf16x4*)(&Ps[wid][(qs * 16 + l15) * 72 + lb * 16 + quad * 4]) = pk;
            }
        }

        // V A-fragments: read once, reused across 4 q-subtiles
        bf16x8 av[2][4];
#pragma unroll
        for (int ks = 0; ks < 2; ks++)
#pragma unroll
            for (int c = 0; c < 4; c++)
                av[ks][c] = *(const bf16x8*)(Vs + (c * 16 + l15) * 72 + ks * 32 + quad * 8);

        // O[kd][q] += V·P
#pragma unroll
        for (int qs = 0; qs < 4; qs++) {
            bf16x8 bp0 = *(const bf16x8*)(&Ps[wid][(qs * 16 + l15) * 72 + quad * 8]);
            bf16x8 bp1 = *(const bf16x8*)(&Ps[wid][(qs * 16 + l15) * 72 + 32 + quad * 8]);
#pragma unroll
            for (int c = 0; c < 4; c++) {
                oacc[c][qs] = __builtin_amdgcn_mfma_f32_16x16x32_bf16(av[0][c], bp0, oacc[c][qs], 0, 0, 0);
                oacc[c][qs] = __builtin_amdgcn_mfma_f32_16x16x32_bf16(av[1][c], bp1, oacc[c][qs], 0, 0, 0);
            }
        }
    }

    // denominators: reduce across quads, quad 0 writes
#pragma unroll
    for (int qs = 0; qs < 4; qs++) {
        float l = ls[qs];
        l += __shfl_xor(l, 16, 64);
        l += __shfl_xor(l, 32, 64);
        if (quad == 0)
            Lsum[split * 32768 + h * 4096 + qw + qs * 16 + l15] = l;
    }

    // partial O (unnormalized, bf16): [512 rows][4096 q]
    bf16* Ob = Opart + split * 2097152;
#pragma unroll
    for (int c = 0; c < 4; c++)
#pragma unroll
        for (int qs = 0; qs < 4; qs++)
#pragma unroll
            for (int r = 0; r < 4; r++)
                Ob[(h * 64 + c * 16 + quad * 4 + r) * 4096 + qw + qs * 16 + l15] = (bf16)oacc[c][qs][r];
}

// ---------------- K5: combine 4 splits + normalize ----------------
__global__ void k_final(const bf16* __restrict__ Opart, const float* __restrict__ Lsum,
                        float* __restrict__ out) {
    int gid = blockIdx.x * 256 + threadIdx.x;    // 262144
    int row = gid >> 9;
    int c8  = (gid & 511) << 3;
    int h   = row >> 6;
    float o[8] = {0, 0, 0, 0, 0, 0, 0, 0};
    float l[8] = {0, 0, 0, 0, 0, 0, 0, 0};
#pragma unroll
    for (int s = 0; s < 4; s++) {
        bf16x8 v = *(const bf16x8*)(Opart + s * 2097152 + row * 4096 + c8);
        const float* L = Lsum + s * 32768 + h * 4096 + c8;
        float4 l0 = *(const float4*)L;
        float4 l1 = *(const float4*)(L + 4);
#pragma unroll
        for (int j = 0; j < 8; j++) o[j] += (float)v[j];
        l[0] += l0.x; l[1] += l0.y; l[2] += l0.z; l[3] += l0.w;
        l[4] += l1.x; l[5] += l1.y; l[6] += l1.z; l[7] += l1.w;
    }
    float4 r0, r1;
    r0.x = o[0] / l[0]; r0.y = o[1] / l[1]; r0.z = o[2] / l[2]; r0.w = o[3] / l[3];
    r1.x = o[4] / l[4]; r1.y = o[5] / l[5]; r1.z = o[6] / l[6]; r1.w = o[7] / l[7];
    *(float4*)(out + row * 4096 + c8)     = r0;
    *(float4*)(out + row * 4096 + c8 + 4) = r1;
}

extern "C" void kernel_launch(void* const* d_in, const int* in_sizes, int n_in,
                              void* d_out, int out_size, void* d_ws, size_t ws_size,
                              hipStream_t stream) {
    const float* x      = (const float*)d_in[0];
    const float* conv_w = (const float*)d_in[1];
    const float* gn_w   = (const float*)d_in[2];
    const float* gn_b   = (const float*)d_in[3];
    float* out = (float*)d_out;
    char* ws = (char*)d_ws;

    bf16*   qkvT  = (bf16*) (ws);                   // 6291456 bf16  = 12 MB
    bf16*   Opart = (bf16*) (ws + 12582912);        // 4 x 2097152 bf16 = 16 MB
    bf16*   Wb    = (bf16*) (ws + 29360128);        // 768 KB
    bf16*   xT    = (bf16*) (ws + 30146560);        // 2 MB
    float*  cs    = (float*)(ws + 32243712);        // 1536 float2 = 12 KB
    float2* ab    = (float2*)(ws + 32256000);       // 1536 float2 = 12 KB
    float*  Lsum  = (float*)(ws + 32268288);        // 4 x 32768 f32 = 512 KB
                                                    // total 32.8 MB (< proven 40.6 MB)

    hipLaunchKernelGGL(k_misc,  dim3(897),  dim3(256), 0, stream, x, conv_w, xT, Wb, cs);
    hipLaunchKernelGGL(k_conv,  dim3(1536), dim3(256), 0, stream, Wb, xT, qkvT, cs);
    hipLaunchKernelGGL(k_stats, dim3(24),   dim3(64),  0, stream, (const float2*)cs, gn_w, gn_b, ab);
    hipLaunchKernelGGL(k_norm,  dim3(3072), dim3(256), 0, stream, qkvT, (const float2*)ab);
    hipLaunchKernelGGL(k_attn,  dim3(512),  dim3(256), 0, stream, qkvT, Opart, Lsum);
    hipLaunchKernelGGL(k_final, dim3(1024), dim3(256), 0, stream, Opart, Lsum, out);
}